// Round 3
// baseline (419.961 us; speedup 1.0000x reference)
//
#include <hip/hip_runtime.h>

#define HIDDEN 128
#define P_NUM 8
#define PLEN 4
#define ETYPES 2
#define BN 32                      // nodes per block
#define APAD 8                     // bf16 pad per A row (row stride 528 B -> 2-way bank alias, free)
#define AROW (2*HIDDEN + APAD)     // 264 bf16

typedef __attribute__((ext_vector_type(8))) short short8;
typedef __attribute__((ext_vector_type(4))) float floatx4;

__device__ __forceinline__ unsigned short f2bf(float x) {
  unsigned int u = __float_as_uint(x);
  u += 0x7FFFu + ((u >> 16) & 1u);   // round-to-nearest-even
  return (unsigned short)(u >> 16);
}
__device__ __forceinline__ float bf2f(unsigned short u) {
  return __uint_as_float(((unsigned int)u) << 16);
}

// ---- feats f32 -> bf16 into workspace (one-shot, BW-bound ~13us) ----
__global__ __launch_bounds__(256) void cvt_bf16(const float* __restrict__ in,
                                                unsigned short* __restrict__ out, int n4) {
  int i = blockIdx.x * blockDim.x + threadIdx.x;
  if (i < n4) {
    float4 f = ((const float4*)in)[i];
    ushort4 u = make_ushort4(f2bf(f.x), f2bf(f.y), f2bf(f.z), f2bf(f.w));
    ((ushort4*)out)[i] = u;
  }
}

template<bool BF>
__global__ __launch_bounds__(256, 4) void impeller_fused(
    const void* __restrict__ feats_v,
    const int* __restrict__ paths,
    const int* __restrict__ ptypes,
    const float* __restrict__ pweights,
    const float* __restrict__ Wfc,
    float* __restrict__ out,
    int n_nodes)
{
  __shared__ __align__(16) unsigned short A[BN * AROW];   // 16896 B
  __shared__ int idx_lds[P_NUM * BN * PLEN];              // 4096 B
  __shared__ float2 cw[P_NUM * PLEN];                     // 256 B
  // total ~21.3 KB -> LDS allows 7 blocks/CU; VGPR (<=128) caps at 4 waves/SIMD = 16 waves/CU

  const int tid = threadIdx.x;
  const int n0 = blockIdx.x * BN;

  // ---- stage this block's path indices (two 512B coalesced segments per step) ----
  #pragma unroll
  for (int i = tid; i < P_NUM * BN * PLEN; i += 256) {
    int p = i >> 7;            // / (BN*PLEN)
    int off = i & (BN * PLEN - 1);
    int g = n0 * PLEN + off;
    int v = 0;
    if (g < n_nodes * PLEN) v = paths[(size_t)p * n_nodes * PLEN + g];
    idx_lds[i] = v;
  }

  // ---- combined weights: route w[type,l]/cnt_type to acc0 (type0) / acc1 (type1) ----
  if (tid < P_NUM * PLEN) {
    int p = tid >> 2, l = tid & 3;
    int cnt0 = 0;
    #pragma unroll
    for (int q = 0; q < P_NUM; ++q) cnt0 += (ptypes[q] == 0);
    int cnt1 = P_NUM - cnt0;
    int t = ptypes[p];
    float w = pweights[t * PLEN + l];
    float2 c;
    c.x = (t == 0) ? w / (float)cnt0 : 0.f;
    c.y = (t == 1) ? w / (float)cnt1 : 0.f;
    cw[tid] = c;
  }
  __syncthreads();

  // ---- gather + weighted sum: 16 lanes/node, 8 dims/thread (16 B/lane loads) ----
  const int ng = tid >> 4;          // node slot 0..15
  const int d8 = (tid & 15) * 8;    // feature dims [d8, d8+8)
  #pragma unroll 1
  for (int it = 0; it < BN / 16; ++it) {
    const int nl = it * 16 + ng;
    float a0[8], a1[8];
    #pragma unroll
    for (int k = 0; k < 8; ++k) { a0[k] = 0.f; a1[k] = 0.f; }

    #pragma unroll
    for (int p = 0; p < P_NUM; ++p) {
      #pragma unroll
      for (int l = 0; l < PLEN; ++l) {
        int idx = idx_lds[p * (BN * PLEN) + nl * PLEN + l];   // LDS broadcast (16-lane groups)
        float2 c = cw[p * PLEN + l];
        if (BF) {
          const short8 f = *(const short8*)((const unsigned short*)feats_v + (size_t)idx * HIDDEN + d8);
          #pragma unroll
          for (int k = 0; k < 8; ++k) {
            float v = bf2f((unsigned short)f[k]);
            a0[k] += c.x * v; a1[k] += c.y * v;
          }
        } else {
          const float* fp = (const float*)feats_v + (size_t)idx * HIDDEN + d8;
          const float4 fa = *(const float4*)fp;
          const float4 fb = *(const float4*)(fp + 4);
          float v[8] = {fa.x, fa.y, fa.z, fa.w, fb.x, fb.y, fb.z, fb.w};
          #pragma unroll
          for (int k = 0; k < 8; ++k) { a0[k] += c.x * v[k]; a1[k] += c.y * v[k]; }
        }
      }
    }
    short8 u0, u1;
    #pragma unroll
    for (int k = 0; k < 8; ++k) {
      u0[k] = (short)f2bf(a0[k]);
      u1[k] = (short)f2bf(a1[k]);
    }
    *(short8*)&A[nl * AROW + d8] = u0;            // fout[:, 0:128]   (type-0 mean)
    *(short8*)&A[nl * AROW + HIDDEN + d8] = u1;   // fout[:, 128:256] (type-1 mean)
  }
  __syncthreads();

  // ---- MFMA GEMM: out(32x128) = A(32x256) @ Wfc^T(256x128), 16x16x32 bf16 ----
  const int wid = tid >> 6;         // wave 0..3 -> output cols [wid*32, wid*32+32)
  const int lane = tid & 63;
  const int q = lane >> 4;          // quad 0..3
  const int r = lane & 15;

  floatx4 acc[2][2];
  #pragma unroll
  for (int mt = 0; mt < 2; ++mt)
    #pragma unroll
    for (int jt = 0; jt < 2; ++jt)
      acc[mt][jt] = (floatx4){0.f, 0.f, 0.f, 0.f};

  #pragma unroll
  for (int kk = 0; kk < 8; ++kk) {
    short8 af[2];
    #pragma unroll
    for (int mt = 0; mt < 2; ++mt)
      af[mt] = *(const short8*)&A[(mt * 16 + r) * AROW + kk * 32 + q * 8];

    short8 bfr[2];
    #pragma unroll
    for (int jt = 0; jt < 2; ++jt) {
      const int j = wid * 32 + jt * 16 + r;                   // output col = Wfc row
      const float* wp = Wfc + (size_t)j * (ETYPES * HIDDEN) + kk * 32 + q * 8;
      const float4 wa = *(const float4*)wp;
      const float4 wb = *(const float4*)(wp + 4);
      short8 b;
      b[0] = (short)f2bf(wa.x); b[1] = (short)f2bf(wa.y);
      b[2] = (short)f2bf(wa.z); b[3] = (short)f2bf(wa.w);
      b[4] = (short)f2bf(wb.x); b[5] = (short)f2bf(wb.y);
      b[6] = (short)f2bf(wb.z); b[7] = (short)f2bf(wb.w);
      bfr[jt] = b;
    }

    #pragma unroll
    for (int mt = 0; mt < 2; ++mt)
      #pragma unroll
      for (int jt = 0; jt < 2; ++jt)
        acc[mt][jt] = __builtin_amdgcn_mfma_f32_16x16x32_bf16(af[mt], bfr[jt], acc[mt][jt], 0, 0, 0);
  }

  // ---- epilogue: relu + store. D layout: col = lane&15, row = q*4 + reg ----
  #pragma unroll
  for (int mt = 0; mt < 2; ++mt) {
    const int node_base = n0 + mt * 16 + q * 4;
    #pragma unroll
    for (int jt = 0; jt < 2; ++jt) {
      const int j = wid * 32 + jt * 16 + r;
      #pragma unroll
      for (int reg = 0; reg < 4; ++reg) {
        const int nn = node_base + reg;
        if (nn < n_nodes) out[(size_t)nn * HIDDEN + j] = fmaxf(acc[mt][jt][reg], 0.f);
      }
    }
  }
}

extern "C" void kernel_launch(void* const* d_in, const int* in_sizes, int n_in,
                              void* d_out, int out_size, void* d_ws, size_t ws_size,
                              hipStream_t stream) {
  const float* feats    = (const float*)d_in[0];
  const int*   paths    = (const int*)d_in[1];
  const int*   ptypes   = (const int*)d_in[2];
  const float* pweights = (const float*)d_in[3];
  const float* Wfc      = (const float*)d_in[4];
  float* out = (float*)d_out;

  const int n_nodes = in_sizes[0] / HIDDEN;
  const int blocks = (n_nodes + BN - 1) / BN;
  const size_t need = (size_t)in_sizes[0] * sizeof(unsigned short);

  if (ws_size >= need) {
    unsigned short* feats_bf = (unsigned short*)d_ws;
    const int n4 = in_sizes[0] / 4;
    hipLaunchKernelGGL(cvt_bf16, dim3((n4 + 255) / 256), dim3(256), 0, stream,
                       feats, feats_bf, n4);
    hipLaunchKernelGGL((impeller_fused<true>), dim3(blocks), dim3(256), 0, stream,
                       (const void*)feats_bf, paths, ptypes, pweights, Wfc, out, n_nodes);
  } else {
    hipLaunchKernelGGL((impeller_fused<false>), dim3(blocks), dim3(256), 0, stream,
                       (const void*)feats, paths, ptypes, pweights, Wfc, out, n_nodes);
  }
}

// Round 4
// 298.323 us; speedup vs baseline: 1.4077x; 1.4077x over previous
//
#include <hip/hip_runtime.h>

#define HIDDEN 128
#define P_NUM 8
#define PLEN 4
#define ETYPES 2
#define BN 32                      // nodes per block (R3's occupancy win)
#define APAD 8                     // bf16 pad per A row (528 B stride -> 2-way alias, free)
#define AROW (2*HIDDEN + APAD)     // 264 bf16

typedef __attribute__((ext_vector_type(8))) short short8;
typedef __attribute__((ext_vector_type(4))) float floatx4;

__device__ __forceinline__ unsigned short f2bf(float x) {
  unsigned int u = __float_as_uint(x);
  u += 0x7FFFu + ((u >> 16) & 1u);   // round-to-nearest-even
  return (unsigned short)(u >> 16);
}
__device__ __forceinline__ float bf2f(unsigned short u) {
  return __uint_as_float(((unsigned int)u) << 16);
}

// ---- feats f32 -> bf16 into workspace (one-shot, BW-bound ~13us) ----
__global__ __launch_bounds__(256) void cvt_bf16(const float* __restrict__ in,
                                                unsigned short* __restrict__ out, int n4) {
  int i = blockIdx.x * blockDim.x + threadIdx.x;
  if (i < n4) {
    float4 f = ((const float4*)in)[i];
    ushort4 u = make_ushort4(f2bf(f.x), f2bf(f.y), f2bf(f.z), f2bf(f.w));
    ((ushort4*)out)[i] = u;
  }
}

template<bool BF>
__global__ __launch_bounds__(256, 3) void impeller_fused(   // budget 170 VGPR: R2-proven no-spill
    const void* __restrict__ feats_v,
    const int* __restrict__ paths,
    const int* __restrict__ ptypes,
    const float* __restrict__ pweights,
    const float* __restrict__ Wfc,
    float* __restrict__ out,
    int n_nodes)
{
  __shared__ __align__(16) unsigned short A[BN * AROW];   // 16896 B
  __shared__ int idx_lds[P_NUM * BN * PLEN];              // 4096 B
  __shared__ float2 cw[P_NUM * PLEN];                     // 256 B
  // ~21.3 KB LDS -> 7 blocks/CU by LDS; VGPR ~84 -> ~6 blocks/CU effective

  const int tid = threadIdx.x;
  const int n0 = blockIdx.x * BN;

  // ---- stage this block's path indices (coalesced 512B segments) ----
  #pragma unroll
  for (int i = tid; i < P_NUM * BN * PLEN; i += 256) {
    int p = i >> 7;                  // / (BN*PLEN) = /128
    int off = i & (BN * PLEN - 1);
    int g = n0 * PLEN + off;
    int v = 0;
    if (g < n_nodes * PLEN) v = paths[(size_t)p * n_nodes * PLEN + g];
    idx_lds[i] = v;
  }

  // ---- combined weights: route w[type,l]/cnt_type to acc0 (type0) / acc1 (type1) ----
  if (tid < P_NUM * PLEN) {
    int p = tid >> 2, l = tid & 3;
    int cnt0 = 0;
    #pragma unroll
    for (int q = 0; q < P_NUM; ++q) cnt0 += (ptypes[q] == 0);
    int cnt1 = P_NUM - cnt0;
    int t = ptypes[p];
    float w = pweights[t * PLEN + l];
    float2 c;
    c.x = (t == 0) ? w / (float)cnt0 : 0.f;
    c.y = (t == 1) ? w / (float)cnt1 : 0.f;
    cw[tid] = c;
  }
  __syncthreads();

  // ---- gather + weighted sum: 32 lanes/node, 4 dims/thread (R2-proven body) ----
  const int ng = tid >> 5;          // node slot 0..7
  const int d4 = (tid & 31) * 4;    // feature dims [d4, d4+4)
  #pragma unroll 1
  for (int it = 0; it < BN / 8; ++it) {
    const int nl = it * 8 + ng;
    float a0x = 0.f, a0y = 0.f, a0z = 0.f, a0w = 0.f;
    float a1x = 0.f, a1y = 0.f, a1z = 0.f, a1w = 0.f;
    #pragma unroll
    for (int p = 0; p < P_NUM; ++p) {
      #pragma unroll
      for (int l = 0; l < PLEN; ++l) {
        int idx = idx_lds[p * (BN * PLEN) + nl * PLEN + l];   // LDS broadcast
        float2 c = cw[p * PLEN + l];
        float fx, fy, fz, fw;
        if (BF) {
          const ushort4 fu = *(const ushort4*)((const unsigned short*)feats_v + (size_t)idx * HIDDEN + d4);
          fx = bf2f(fu.x); fy = bf2f(fu.y); fz = bf2f(fu.z); fw = bf2f(fu.w);
        } else {
          const float4 f = *(const float4*)((const float*)feats_v + (size_t)idx * HIDDEN + d4);
          fx = f.x; fy = f.y; fz = f.z; fw = f.w;
        }
        a0x += c.x * fx; a0y += c.x * fy; a0z += c.x * fz; a0w += c.x * fw;
        a1x += c.y * fx; a1y += c.y * fy; a1z += c.y * fz; a1w += c.y * fw;
      }
    }
    ushort4 u0 = make_ushort4(f2bf(a0x), f2bf(a0y), f2bf(a0z), f2bf(a0w));
    ushort4 u1 = make_ushort4(f2bf(a1x), f2bf(a1y), f2bf(a1z), f2bf(a1w));
    *(ushort4*)&A[nl * AROW + d4] = u0;            // fout[:, 0:128]   (type-0 mean)
    *(ushort4*)&A[nl * AROW + HIDDEN + d4] = u1;   // fout[:, 128:256] (type-1 mean)
  }
  __syncthreads();

  // ---- MFMA GEMM: out(32x128) = A(32x256) @ Wfc^T(256x128), 16x16x32 bf16 ----
  const int wid = tid >> 6;         // wave -> output cols [wid*32, wid*32+32)
  const int lane = tid & 63;
  const int q = lane >> 4;
  const int r = lane & 15;

  floatx4 acc[2][2];
  #pragma unroll
  for (int mt = 0; mt < 2; ++mt)
    #pragma unroll
    for (int jt = 0; jt < 2; ++jt)
      acc[mt][jt] = (floatx4){0.f, 0.f, 0.f, 0.f};

  #pragma unroll
  for (int kk = 0; kk < 8; ++kk) {
    short8 af[2];
    #pragma unroll
    for (int mt = 0; mt < 2; ++mt)
      af[mt] = *(const short8*)&A[(mt * 16 + r) * AROW + kk * 32 + q * 8];

    short8 bfr[2];
    #pragma unroll
    for (int jt = 0; jt < 2; ++jt) {
      const int j = wid * 32 + jt * 16 + r;                   // output col = Wfc row
      const float* wp = Wfc + (size_t)j * (ETYPES * HIDDEN) + kk * 32 + q * 8;
      const float4 wa = *(const float4*)wp;
      const float4 wb = *(const float4*)(wp + 4);
      short8 b;
      b[0] = (short)f2bf(wa.x); b[1] = (short)f2bf(wa.y);
      b[2] = (short)f2bf(wa.z); b[3] = (short)f2bf(wa.w);
      b[4] = (short)f2bf(wb.x); b[5] = (short)f2bf(wb.y);
      b[6] = (short)f2bf(wb.z); b[7] = (short)f2bf(wb.w);
      bfr[jt] = b;
    }

    #pragma unroll
    for (int mt = 0; mt < 2; ++mt)
      #pragma unroll
      for (int jt = 0; jt < 2; ++jt)
        acc[mt][jt] = __builtin_amdgcn_mfma_f32_16x16x32_bf16(af[mt], bfr[jt], acc[mt][jt], 0, 0, 0);
  }

  // ---- epilogue: relu + store. D layout: col = lane&15, row = q*4 + reg ----
  #pragma unroll
  for (int mt = 0; mt < 2; ++mt) {
    const int node_base = n0 + mt * 16 + q * 4;
    #pragma unroll
    for (int jt = 0; jt < 2; ++jt) {
      const int j = wid * 32 + jt * 16 + r;
      #pragma unroll
      for (int reg = 0; reg < 4; ++reg) {
        const int nn = node_base + reg;
        if (nn < n_nodes) out[(size_t)nn * HIDDEN + j] = fmaxf(acc[mt][jt][reg], 0.f);
      }
    }
  }
}

extern "C" void kernel_launch(void* const* d_in, const int* in_sizes, int n_in,
                              void* d_out, int out_size, void* d_ws, size_t ws_size,
                              hipStream_t stream) {
  const float* feats    = (const float*)d_in[0];
  const int*   paths    = (const int*)d_in[1];
  const int*   ptypes   = (const int*)d_in[2];
  const float* pweights = (const float*)d_in[3];
  const float* Wfc      = (const float*)d_in[4];
  float* out = (float*)d_out;

  const int n_nodes = in_sizes[0] / HIDDEN;
  const int blocks = (n_nodes + BN - 1) / BN;
  const size_t need = (size_t)in_sizes[0] * sizeof(unsigned short);

  if (ws_size >= need) {
    unsigned short* feats_bf = (unsigned short*)d_ws;
    const int n4 = in_sizes[0] / 4;
    hipLaunchKernelGGL(cvt_bf16, dim3((n4 + 255) / 256), dim3(256), 0, stream,
                       feats, feats_bf, n4);
    hipLaunchKernelGGL((impeller_fused<true>), dim3(blocks), dim3(256), 0, stream,
                       (const void*)feats_bf, paths, ptypes, pweights, Wfc, out, n_nodes);
  } else {
    hipLaunchKernelGGL((impeller_fused<false>), dim3(blocks), dim3(256), 0, stream,
                       (const void*)feats, paths, ptypes, pweights, Wfc, out, n_nodes);
  }
}

// Round 5
// 224.862 us; speedup vs baseline: 1.8676x; 1.3267x over previous
//
#include <hip/hip_runtime.h>

#define HIDDEN 128
#define P_NUM 8
#define PLEN 4
#define ETYPES 2
#define BN 32                      // nodes per block (100000 = 3125*32, no tail)
#define APAD 8
#define AROW (2*HIDDEN + APAD)     // 264 bf16

typedef __attribute__((ext_vector_type(8))) short short8;
typedef __attribute__((ext_vector_type(4))) float floatx4;

__device__ __forceinline__ unsigned short f2bf(float x) {
  unsigned int u = __float_as_uint(x);
  u += 0x7FFFu + ((u >> 16) & 1u);
  return (unsigned short)(u >> 16);
}
__device__ __forceinline__ float bf2f(unsigned short u) {
  return __uint_as_float(((unsigned int)u) << 16);
}

__global__ __launch_bounds__(256) void cvt_bf16(const float* __restrict__ in,
                                                unsigned short* __restrict__ out, int n4) {
  int i = blockIdx.x * blockDim.x + threadIdx.x;
  if (i < n4) {
    float4 f = ((const float4*)in)[i];
    ((ushort4*)out)[i] = make_ushort4(f2bf(f.x), f2bf(f.y), f2bf(f.z), f2bf(f.w));
  }
}

__global__ __launch_bounds__(256, 3) void impeller_fused(
    const unsigned short* __restrict__ feats,   // bf16, N x 128
    const int* __restrict__ paths,
    const int* __restrict__ ptypes,
    const float* __restrict__ pweights,
    const float* __restrict__ Wfc,
    float* __restrict__ out,
    int n_nodes)
{
  __shared__ __align__(16) unsigned short A[BN * AROW];   // 16896 B
  __shared__ __align__(16) int idx_lds[P_NUM * BN * PLEN];// 4096 B
  __shared__ float2 cw[P_NUM * PLEN];                     // 256 B

  const int tid = threadIdx.x;
  const int n0 = blockIdx.x * BN;

  // ---- stage path indices (coalesced) ----
  #pragma unroll
  for (int i = tid; i < P_NUM * BN * PLEN; i += 256) {
    int p = i >> 7;                  // / (BN*PLEN)=128
    int off = i & (BN * PLEN - 1);
    idx_lds[i] = paths[(size_t)p * n_nodes * PLEN + n0 * PLEN + off];
  }

  if (tid < P_NUM * PLEN) {
    int p = tid >> 2, l = tid & 3;
    int cnt0 = 0;
    #pragma unroll
    for (int q = 0; q < P_NUM; ++q) cnt0 += (ptypes[q] == 0);
    int cnt1 = P_NUM - cnt0;
    int t = ptypes[p];
    float w = pweights[t * PLEN + l];
    float2 c;
    c.x = (t == 0) ? w / (float)cnt0 : 0.f;
    c.y = (t == 1) ? w / (float)cnt1 : 0.f;
    cw[tid] = c;
  }
  __syncthreads();

  // ---- gather: wave = 4 groups x 16 lanes; group g owns p=g and p=g+4 ----
  const int wv = tid >> 6;          // wave 0..3 -> nodes wv*8 .. wv*8+7
  const int lane = tid & 63;
  const int g = lane >> 4;          // group 0..3
  const int r = lane & 15;          // 8 dims per lane: [r*8, r*8+8)

  // loop-invariant combined weights for this lane's chain: j -> (p = g+4*(j>>2), l = j&3)
  float cx[8], cy[8];
  #pragma unroll
  for (int j = 0; j < 8; ++j) {
    float2 c = cw[(g + 4 * (j >> 2)) * PLEN + (j & 3)];
    cx[j] = c.x; cy[j] = c.y;
  }

  #pragma unroll 1
  for (int it = 0; it < 4; ++it) {
    const int nA = wv * 8 + it * 2;
    const int nB = nA + 1;
    // idx for both nodes: 2 x ds_read_b128 each (16B-aligned)
    int4 iA0 = *(const int4*)&idx_lds[g * (BN * PLEN) + nA * PLEN];
    int4 iA1 = *(const int4*)&idx_lds[(g + 4) * (BN * PLEN) + nA * PLEN];
    int4 iB0 = *(const int4*)&idx_lds[g * (BN * PLEN) + nB * PLEN];
    int4 iB1 = *(const int4*)&idx_lds[(g + 4) * (BN * PLEN) + nB * PLEN];
    int ia[8] = {iA0.x, iA0.y, iA0.z, iA0.w, iA1.x, iA1.y, iA1.z, iA1.w};
    int ib[8] = {iB0.x, iB0.y, iB0.z, iB0.w, iB1.x, iB1.y, iB1.z, iB1.w};

    // issue all 16 gathers back-to-back (idx in regs -> independent)
    short8 fa[8], fb[8];
    #pragma unroll
    for (int j = 0; j < 8; ++j)
      fa[j] = *(const short8*)(feats + (size_t)ia[j] * HIDDEN + r * 8);
    #pragma unroll
    for (int j = 0; j < 8; ++j)
      fb[j] = *(const short8*)(feats + (size_t)ib[j] * HIDDEN + r * 8);

    // ---- node A: accumulate, reduce across groups, store ----
    {
      float a0[8], a1[8];
      #pragma unroll
      for (int k = 0; k < 8; ++k) { a0[k] = 0.f; a1[k] = 0.f; }
      #pragma unroll
      for (int j = 0; j < 8; ++j) {
        #pragma unroll
        for (int k = 0; k < 8; ++k) {
          float v = bf2f((unsigned short)fa[j][k]);
          a0[k] += cx[j] * v; a1[k] += cy[j] * v;
        }
      }
      #pragma unroll
      for (int k = 0; k < 8; ++k) {
        a0[k] += __shfl_xor(a0[k], 16); a0[k] += __shfl_xor(a0[k], 32);
        a1[k] += __shfl_xor(a1[k], 16); a1[k] += __shfl_xor(a1[k], 32);
      }
      short8 u;
      if (g == 0) {
        #pragma unroll
        for (int k = 0; k < 8; ++k) u[k] = (short)f2bf(a0[k]);
        *(short8*)&A[nA * AROW + r * 8] = u;
      } else if (g == 1) {
        #pragma unroll
        for (int k = 0; k < 8; ++k) u[k] = (short)f2bf(a1[k]);
        *(short8*)&A[nA * AROW + HIDDEN + r * 8] = u;
      }
    }
    // ---- node B ----
    {
      float a0[8], a1[8];
      #pragma unroll
      for (int k = 0; k < 8; ++k) { a0[k] = 0.f; a1[k] = 0.f; }
      #pragma unroll
      for (int j = 0; j < 8; ++j) {
        #pragma unroll
        for (int k = 0; k < 8; ++k) {
          float v = bf2f((unsigned short)fb[j][k]);
          a0[k] += cx[j] * v; a1[k] += cy[j] * v;
        }
      }
      #pragma unroll
      for (int k = 0; k < 8; ++k) {
        a0[k] += __shfl_xor(a0[k], 16); a0[k] += __shfl_xor(a0[k], 32);
        a1[k] += __shfl_xor(a1[k], 16); a1[k] += __shfl_xor(a1[k], 32);
      }
      short8 u;
      if (g == 0) {
        #pragma unroll
        for (int k = 0; k < 8; ++k) u[k] = (short)f2bf(a0[k]);
        *(short8*)&A[nB * AROW + r * 8] = u;
      } else if (g == 1) {
        #pragma unroll
        for (int k = 0; k < 8; ++k) u[k] = (short)f2bf(a1[k]);
        *(short8*)&A[nB * AROW + HIDDEN + r * 8] = u;
      }
    }
  }
  __syncthreads();

  // ---- MFMA GEMM: out(32x128) = A(32x256) @ Wfc^T(256x128) ----
  const int q = lane >> 4;
  const int rr = lane & 15;

  floatx4 acc[2][2];
  #pragma unroll
  for (int mt = 0; mt < 2; ++mt)
    #pragma unroll
    for (int jt = 0; jt < 2; ++jt)
      acc[mt][jt] = (floatx4){0.f, 0.f, 0.f, 0.f};

  #pragma unroll
  for (int kk = 0; kk < 8; ++kk) {
    short8 af[2];
    #pragma unroll
    for (int mt = 0; mt < 2; ++mt)
      af[mt] = *(const short8*)&A[(mt * 16 + rr) * AROW + kk * 32 + q * 8];

    short8 bfr[2];
    #pragma unroll
    for (int jt = 0; jt < 2; ++jt) {
      const int j = wv * 32 + jt * 16 + rr;
      const float* wp = Wfc + (size_t)j * (ETYPES * HIDDEN) + kk * 32 + q * 8;
      const float4 wa = *(const float4*)wp;
      const float4 wb = *(const float4*)(wp + 4);
      short8 b;
      b[0] = (short)f2bf(wa.x); b[1] = (short)f2bf(wa.y);
      b[2] = (short)f2bf(wa.z); b[3] = (short)f2bf(wa.w);
      b[4] = (short)f2bf(wb.x); b[5] = (short)f2bf(wb.y);
      b[6] = (short)f2bf(wb.z); b[7] = (short)f2bf(wb.w);
      bfr[jt] = b;
    }

    #pragma unroll
    for (int mt = 0; mt < 2; ++mt)
      #pragma unroll
      for (int jt = 0; jt < 2; ++jt)
        acc[mt][jt] = __builtin_amdgcn_mfma_f32_16x16x32_bf16(af[mt], bfr[jt], acc[mt][jt], 0, 0, 0);
  }

  #pragma unroll
  for (int mt = 0; mt < 2; ++mt) {
    const int node_base = n0 + mt * 16 + q * 4;
    #pragma unroll
    for (int jt = 0; jt < 2; ++jt) {
      const int j = wv * 32 + jt * 16 + rr;
      #pragma unroll
      for (int reg = 0; reg < 4; ++reg) {
        const int nn = node_base + reg;
        if (nn < n_nodes) out[(size_t)nn * HIDDEN + j] = fmaxf(acc[mt][jt][reg], 0.f);
      }
    }
  }
}

extern "C" void kernel_launch(void* const* d_in, const int* in_sizes, int n_in,
                              void* d_out, int out_size, void* d_ws, size_t ws_size,
                              hipStream_t stream) {
  const float* feats    = (const float*)d_in[0];
  const int*   paths    = (const int*)d_in[1];
  const int*   ptypes   = (const int*)d_in[2];
  const float* pweights = (const float*)d_in[3];
  const float* Wfc      = (const float*)d_in[4];
  float* out = (float*)d_out;

  const int n_nodes = in_sizes[0] / HIDDEN;
  const int blocks = (n_nodes + BN - 1) / BN;

  unsigned short* feats_bf = (unsigned short*)d_ws;
  const int n4 = in_sizes[0] / 4;
  hipLaunchKernelGGL(cvt_bf16, dim3((n4 + 255) / 256), dim3(256), 0, stream,
                     feats, feats_bf, n4);
  hipLaunchKernelGGL(impeller_fused, dim3(blocks), dim3(256), 0, stream,
                     feats_bf, paths, ptypes, pweights, Wfc, out, n_nodes);
}